// Round 7
// baseline (216.739 us; speedup 1.0000x reference)
//
#include <hip/hip_runtime.h>
#include <hip/hip_bf16.h>

#define LL 4
#define NN 50000
#define DD 64
#define EE 500000
#define HID 256
#define KDIM 512
#define LN_EPS 1e-5f

typedef __bf16 bf16x8 __attribute__((ext_vector_type(8)));
typedef float f32x16 __attribute__((ext_vector_type(16)));

__device__ __forceinline__ void async16(const void* g, void* l) {
    __builtin_amdgcn_global_load_lds(
        (const __attribute__((address_space(1))) void*)g,
        (__attribute__((address_space(3))) void*)l, 16, 0, 0);
}

// ---------- kernel 1: W1 (256x512 f32) -> W'' (512 out-cols x 256 K) bf16 ----
// Out-col j<256: Ps row j (src cols of W1); j>=256: Pd row j-256 (dst cols).
// K index k means feature (l = k>>6, d = k&63) -> W1 col l*128 + 64*(j>=256) + d.
// Chunk layout: w2c[(b*512 + j)*8 + z], chunk b covers k in [8b, 8b+8).
__global__ void w2_conv(const float* __restrict__ w1, __bf16* __restrict__ o) {
    int t = blockIdx.x * 256 + threadIdx.x;                 // 16384 threads
    int j  = t & 511;
    int b  = t >> 9;              // [0,32)
    int k0 = (b >> 1) * 16 + (b & 1) * 8;                   // == 8*b
    int r  = j & 255;
    int col = (k0 >> 6) * 128 + ((j >> 8) ? 64 : 0) + (k0 & 63);
    const float4* p = (const float4*)(w1 + r * KDIM + col);
    float4 va = p[0];
    float4 vb = p[1];
    bf16x8 v;
    v[0] = (__bf16)va.x; v[1] = (__bf16)va.y; v[2] = (__bf16)va.z; v[3] = (__bf16)va.w;
    v[4] = (__bf16)vb.x; v[5] = (__bf16)vb.y; v[6] = (__bf16)vb.z; v[7] = (__bf16)vb.w;
    *(bf16x8*)(o + (size_t)t * 8) = v;
}

// ---------- kernel 2: FUSED tanh + node projections (8-phase pipeline) ------
// P[n][512] = [Ps | Pd+b1] (bf16). Grid 391. 256 thr / 4 waves; 128-node tile.
// Round-7 restructuring (R6 serialized stage->drain->MFMA->bounce->store x4):
//  - 64-col B slices (32 KB) double-buffered in 64 KB LDS, 8 phases.
//    stage(p+1) is issued BEFORE phase p's MFMA, so the end-of-phase
//    __syncthreads drains an already-landed transfer (T3-minimum pipeline).
//  - C stored DIRECTLY from the 32x32 fragment layout (no LDS bounce):
//    for fixed r, the 32 lanes of each half write 64 contiguous bytes.
//  - launch_bounds(256,4) caps VGPR at 128 -> 2 blocks/CU with 64 KB LDS.
__global__ __launch_bounds__(256, 4)
void node_proj(const float* __restrict__ h, const __bf16* __restrict__ w2c,
               const float* __restrict__ b1, __bf16* __restrict__ P) {
    __shared__ __align__(16) __bf16 Bs[2][16384];   // 2 x 32 KB

    const int tid  = threadIdx.x;
    const int wave = tid >> 6;
    const int lane = tid & 63;
    const int h32  = lane >> 5;
    const int c32  = lane & 31;
    const int n00  = blockIdx.x * 128;

    // stage phase-0 B slice: 32 chunks x 1 KB pieces -> linear 32 KB
    #pragma unroll
    for (int it = 0; it < 8; ++it) {
        int o = it * 2048 + tid * 8;     // elem in [0,16384)
        async16(w2c + (size_t)(o >> 9) * 4096 + (o & 511), &Bs[0][o]);
    }

    // A fragments: read h (f32) once, tanh+scale+convert in registers.
    // frag u: l = u>>2, k = u*16 + h32*8 + z, m = c32 -> node.
    int node = n00 + wave * 32 + c32;
    if (node >= NN) node = NN - 1;
    bf16x8 af[16];
    #pragma unroll
    for (int u = 0; u < 16; ++u) {
        int l = u >> 2;
        float imp = (float)(l + 1) * 0.1f;
        const float* p = h + (size_t)l * (NN * DD) + node * DD
                       + (u & 3) * 16 + h32 * 8;
        float4 va = *(const float4*)p;
        float4 vb = *(const float4*)(p + 4);
        float xv[8] = {va.x, va.y, va.z, va.w, vb.x, vb.y, vb.z, vb.w};
        #pragma unroll
        for (int z = 0; z < 8; ++z) {
            float e2 = __expf(2.0f * (imp * xv[z]));
            af[u][z] = (__bf16)(1.0f - 2.0f / (e2 + 1.0f));
        }
    }

    __syncthreads();   // phase-0 B resident

    for (int p = 0; p < 8; ++p) {
        const int bp = p & 1;
        if (p < 7) {   // issue next stage early: lands during MFMA+stores
            #pragma unroll
            for (int it = 0; it < 8; ++it) {
                int o = it * 2048 + tid * 8;
                async16(w2c + (size_t)(o >> 9) * 4096 + (p + 1) * 512 + (o & 511),
                        &Bs[bp ^ 1][o]);
            }
        }

        f32x16 acc[2];
        acc[0] = (f32x16)(0.f);
        acc[1] = (f32x16)(0.f);
        #pragma unroll
        for (int u = 0; u < 16; ++u) {
            const __bf16* Bk = &Bs[bp][(u * 2 + h32) * 512 + c32 * 8];
            #pragma unroll
            for (int nt = 0; nt < 2; ++nt) {
                bf16x8 bf = *(const bf16x8*)(Bk + nt * 256);
                acc[nt] = __builtin_amdgcn_mfma_f32_32x32x16_bf16(af[u], bf, acc[nt], 0, 0, 0);
            }
        }

        // direct C store: C/D 32x32 layout col=c32, row=(r&3)+8*(r>>2)+4*h32.
        // For fixed r each 32-lane half writes 64 contiguous bytes.
        #pragma unroll
        for (int nt = 0; nt < 2; ++nt) {
            int col = p * 64 + nt * 32 + c32;
            float b1v = (col >= 256) ? b1[col - 256] : 0.f;
            #pragma unroll
            for (int r = 0; r < 16; ++r) {
                int row = (r & 3) + 8 * (r >> 2) + 4 * h32;
                int n = n00 + wave * 32 + row;
                if (n < NN)
                    P[(size_t)n * 512 + col] = (__bf16)(acc[nt][r] + b1v);
            }
        }

        __syncthreads();   // drains stage(p+1) (already landed) + our stores
    }
}

// ---------- kernel 3: per-edge gather + LN + ReLU + dot ---------------------
// Best-measured variant (70.4 us, R2 bench): shfl index broadcast, shfl_xor
// reduces, 3-slot rotation, b1 pre-folded into P. DPP-reduce variant measured
// 72.0-72.2 across two runs (outside within-run spread) -> reverted.
// Across R2-R5 this stage is invariant ~70-72 us under every compute/latency
// restructuring -> cache-hierarchy service bound on the 500 MB random gather.
__global__ __launch_bounds__(256, 3)
void edge_out(const __bf16* __restrict__ P, const int* __restrict__ src,
              const int* __restrict__ dst,
              const float* __restrict__ w3, const float* __restrict__ b3,
              const float* __restrict__ gamma, const float* __restrict__ beta,
              float* __restrict__ out) {
    const int tid = threadIdx.x;
    const int g   = tid >> 4;
    const int j   = tid & 15;

    float gv[16], btv[16], wv[16];
    {
        const float4* pg = (const float4*)(gamma + j * 16);
        const float4* pt = (const float4*)(beta + j * 16);
        const float4* pw = (const float4*)(w3 + j * 16);
        #pragma unroll
        for (int z = 0; z < 4; ++z) {
            float4 vg = pg[z], vt = pt[z], vw = pw[z];
            gv [z*4+0] = vg.x; gv [z*4+1] = vg.y; gv [z*4+2] = vg.z; gv [z*4+3] = vg.w;
            btv[z*4+0] = vt.x; btv[z*4+1] = vt.y; btv[z*4+2] = vt.z; btv[z*4+3] = vt.w;
            wv [z*4+0] = vw.x; wv [z*4+1] = vw.y; wv [z*4+2] = vw.z; wv [z*4+3] = vw.w;
        }
    }
    const float b3v = b3[0];
    const int e0 = blockIdx.x * 128 + g * 8;

    // preload this group's 8 src + 8 dst indices (lane j&7 holds edge e0+(j&7))
    int ep = e0 + (j & 7);
    if (ep >= EE) ep = EE - 1;
    const int sj = src[ep];
    const int dj = dst[ep];

    uint4 s0[3], s1[3], d0[3], d1[3];   // 3-slot rotation, static indices

    #pragma unroll
    for (int i = 0; i < 2; ++i) {       // prologue: edges 0 and 1 in flight
        int s = __shfl(sj, i, 16);
        int d = __shfl(dj, i, 16);
        const uint4* ps = (const uint4*)(P + (size_t)s * 512 + j * 16);
        const uint4* pd = (const uint4*)(P + (size_t)d * 512 + 256 + j * 16);
        s0[i] = ps[0]; s1[i] = ps[1]; d0[i] = pd[0]; d1[i] = pd[1];
    }

    #pragma unroll
    for (int i = 0; i < 8; ++i) {
        if (i + 2 < 8) {                // prefetch edge i+2
            const int slot = (i + 2) % 3;
            int s = __shfl(sj, i + 2, 16);
            int d = __shfl(dj, i + 2, 16);
            const uint4* ps = (const uint4*)(P + (size_t)s * 512 + j * 16);
            const uint4* pd = (const uint4*)(P + (size_t)d * 512 + 256 + j * 16);
            s0[slot] = ps[0]; s1[slot] = ps[1]; d0[slot] = pd[0]; d1[slot] = pd[1];
        }
        const int cs = i % 3;
        bf16x8 a0 = __builtin_bit_cast(bf16x8, s0[cs]);
        bf16x8 a1 = __builtin_bit_cast(bf16x8, s1[cs]);
        bf16x8 c0 = __builtin_bit_cast(bf16x8, d0[cs]);
        bf16x8 c1 = __builtin_bit_cast(bf16x8, d1[cs]);
        float x[16];
        #pragma unroll
        for (int z = 0; z < 8; ++z) {
            x[z]     = (float)a0[z] + (float)c0[z];     // b1 already folded in P
            x[z + 8] = (float)a1[z] + (float)c1[z];
        }
        float sum = 0.f, sq = 0.f;
        #pragma unroll
        for (int z = 0; z < 16; ++z) {
            sum += x[z];
            sq   = fmaf(x[z], x[z], sq);
        }
        #pragma unroll
        for (int m = 1; m < 16; m <<= 1) {
            sum += __shfl_xor(sum, m);
            sq  += __shfl_xor(sq,  m);
        }
        float mu = sum * (1.0f / 256.0f);
        float rs = rsqrtf(sq * (1.0f / 256.0f) - mu * mu + LN_EPS);
        float dot = 0.f;
        #pragma unroll
        for (int z = 0; z < 16; ++z) {
            float y = fmaxf((x[z] - mu) * rs * gv[z] + btv[z], 0.f);
            dot = fmaf(y, wv[z], dot);
        }
        #pragma unroll
        for (int m = 1; m < 16; m <<= 1) dot += __shfl_xor(dot, m);
        int e = e0 + i;
        if (j == 0 && e < EE) out[e] = dot + b3v;
        cs0: ;
    }

    // keep-alive (matches the measured-best build exactly)
    #pragma unroll
    for (int z = 0; z < 16; ++z)
        asm volatile("" :: "v"(gv[z]), "v"(btv[z]), "v"(wv[z]));
}

extern "C" void kernel_launch(void* const* d_in, const int* in_sizes, int n_in,
                              void* d_out, int out_size, void* d_ws, size_t ws_size,
                              hipStream_t stream) {
    const float* h_all  = (const float*)d_in[0];
    const int*   src    = (const int*)  d_in[1];
    const int*   dst    = (const int*)  d_in[2];
    const float* W1     = (const float*)d_in[3];
    const float* b1     = (const float*)d_in[4];
    const float* W3     = (const float*)d_in[5];
    const float* b3     = (const float*)d_in[6];
    const float* gamma2 = (const float*)d_in[7];
    const float* beta2  = (const float*)d_in[8];
    float* out = (float*)d_out;

    __bf16* w2c = (__bf16*)d_ws;                       // 131072 bf16 = 256 KB
    __bf16* P   = w2c + 131072;                        // 50000*512 bf16 = 51.2 MB

    w2_conv<<<64, 256, 0, stream>>>(W1, w2c);
    node_proj<<<(NN + 127) / 128, 256, 0, stream>>>(h_all, w2c, b1, P);
    edge_out<<<(EE + 127) / 128, 256, 0, stream>>>(P, src, dst, W3, b3,
                                                   gamma2, beta2, out);
}

// Round 8
// 194.360 us; speedup vs baseline: 1.1151x; 1.1151x over previous
//
#include <hip/hip_runtime.h>
#include <hip/hip_bf16.h>

#define LL 4
#define NN 50000
#define DD 64
#define EE 500000
#define HID 256
#define KDIM 512
#define LN_EPS 1e-5f

typedef __bf16 bf16x8 __attribute__((ext_vector_type(8)));
typedef float f32x16 __attribute__((ext_vector_type(16)));

__device__ __forceinline__ void async16(const void* g, void* l) {
    __builtin_amdgcn_global_load_lds(
        (const __attribute__((address_space(1))) void*)g,
        (__attribute__((address_space(3))) void*)l, 16, 0, 0);
}

// ---------- kernel 1: W1 (256x512 f32) -> W'' (512 out-cols x 256 K) bf16 ----
// Out-col j<256: Ps row j (src cols of W1); j>=256: Pd row j-256 (dst cols).
// K index k means feature (l = k>>6, d = k&63) -> W1 col l*128 + 64*(j>=256) + d.
// Chunk layout: w2c[(b*512 + j)*8 + z], chunk b covers k in [8b, 8b+8).
__global__ void w2_conv(const float* __restrict__ w1, __bf16* __restrict__ o) {
    int t = blockIdx.x * 256 + threadIdx.x;                 // 16384 threads
    int j  = t & 511;
    int b  = t >> 9;              // [0,32)
    int k0 = (b >> 1) * 16 + (b & 1) * 8;                   // == 8*b
    int r  = j & 255;
    int col = (k0 >> 6) * 128 + ((j >> 8) ? 64 : 0) + (k0 & 63);
    const float4* p = (const float4*)(w1 + r * KDIM + col);
    float4 va = p[0];
    float4 vb = p[1];
    bf16x8 v;
    v[0] = (__bf16)va.x; v[1] = (__bf16)va.y; v[2] = (__bf16)va.z; v[3] = (__bf16)va.w;
    v[4] = (__bf16)vb.x; v[5] = (__bf16)vb.y; v[6] = (__bf16)vb.z; v[7] = (__bf16)vb.w;
    *(bf16x8*)(o + (size_t)t * 8) = v;
}

// ---------- kernel 2: FUSED tanh + node projections (R6 structure) ----------
// P[n][512] = [Ps | Pd+b1] (bf16). Grid 391. This is the measured-best
// node_proj (total 195.1 us in R6). R7's 8-phase/direct-store variant
// regressed +24 us: 32 scalar 2B stores/thread/phase (64B per half-wave)
// vs this version's fully-coalesced bf16x8 bounce rows, and 2x the
// vmcnt-draining barriers. Keep the bounce.
__global__ __launch_bounds__(256, 2)
void node_proj(const float* __restrict__ h, const __bf16* __restrict__ w2c,
               const float* __restrict__ b1, __bf16* __restrict__ P) {
    __shared__ __align__(16) char smem[65536];
    __bf16* Bs  = (__bf16*)smem;      // 64 KB B slice during MFMA
    __bf16* Cs2 = (__bf16*)smem;      // 32 KB bf16 C bounce (phase-separated)

    const int tid  = threadIdx.x;
    const int wave = tid >> 6;
    const int lane = tid & 63;
    const int h32  = lane >> 5;
    const int c32  = lane & 31;
    const int n00  = blockIdx.x * 128;

    // stage B slice for cb=0: 16 x 2KB linear pieces
    #pragma unroll
    for (int it = 0; it < 16; ++it) {
        int o = it * 2048 + tid * 8;   // elem offset within 32768-elem slice
        async16(w2c + (size_t)(o >> 10) * 4096 + (o & 1023), Bs + o);
    }

    // A fragments: read h (f32) once, tanh+scale+convert in registers.
    // frag u: l = u>>2, k-chunk = (u&3)*16 + h32*8, m = c32 -> node.
    int node = n00 + wave * 32 + c32;
    if (node >= NN) node = NN - 1;
    bf16x8 af[16];
    #pragma unroll
    for (int u = 0; u < 16; ++u) {
        int l = u >> 2;
        float imp = (float)(l + 1) * 0.1f;
        const float* p = h + (size_t)l * (NN * DD) + node * DD
                       + (u & 3) * 16 + h32 * 8;
        float4 va = *(const float4*)p;
        float4 vb = *(const float4*)(p + 4);
        float xv[8] = {va.x, va.y, va.z, va.w, vb.x, vb.y, vb.z, vb.w};
        #pragma unroll
        for (int z = 0; z < 8; ++z) {
            float e2 = __expf(2.0f * (imp * xv[z]));
            af[u][z] = (__bf16)(1.0f - 2.0f / (e2 + 1.0f));
        }
    }

    for (int cb = 0; cb < 4; ++cb) {
        __syncthreads();               // B(cb) resident; LDS free of prior phase

        f32x16 acc[4];
        #pragma unroll
        for (int nt = 0; nt < 4; ++nt) acc[nt] = (f32x16)(0.f);

        #pragma unroll
        for (int u = 0; u < 16; ++u) {
            const __bf16* Bk = Bs + (u * 2 + h32) * 1024 + c32 * 8;
            #pragma unroll
            for (int nt = 0; nt < 4; ++nt) {
                bf16x8 bf = *(const bf16x8*)(Bk + nt * 256);
                acc[nt] = __builtin_amdgcn_mfma_f32_32x32x16_bf16(af[u], bf, acc[nt], 0, 0, 0);
            }
        }
        __syncthreads();               // all waves done reading Bs

        // b1 fold for dst half (cols 256..511): col = cb*128 + nt*32 + c32
        float b1v[4];
        #pragma unroll
        for (int nt = 0; nt < 4; ++nt)
            b1v[nt] = (cb >= 2) ? b1[(cb - 2) * 128 + nt * 32 + c32] : 0.f;

        // bounce C (bf16) through LDS for coalesced row stores
        // C/D 32x32 layout: col = c32, row = (r&3) + 8*(r>>2) + 4*h32
        #pragma unroll
        for (int nt = 0; nt < 4; ++nt) {
            #pragma unroll
            for (int r = 0; r < 16; ++r) {
                int nl = wave * 32 + (r & 3) + 8 * (r >> 2) + 4 * h32;
                Cs2[nl * 128 + nt * 32 + c32] = (__bf16)(acc[nt][r] + b1v[nt]);
            }
        }
        __syncthreads();               // Cs2 complete

        #pragma unroll
        for (int it = 0; it < 8; ++it) {
            int o  = it * 2048 + tid * 8;
            int nl = o >> 7;
            int n  = n00 + nl;
            if (n < NN)
                *(bf16x8*)(P + (size_t)n * 512 + cb * 128 + (o & 127)) =
                    *(const bf16x8*)(Cs2 + o);
        }

        if (cb < 3) {
            __syncthreads();           // store-side LDS reads done before overwrite
            #pragma unroll
            for (int it = 0; it < 16; ++it) {
                int o = it * 2048 + tid * 8;
                async16(w2c + (size_t)(o >> 10) * 4096 + (cb + 1) * 1024 + (o & 1023),
                        Bs + o);
            }
        }
    }
}

// ---------- kernel 3: per-edge gather + LN + ReLU + dot ---------------------
// Best-measured variant (69.5-70.4 us across R2/R7 runs): shfl index
// broadcast, shfl_xor reduces, 3-slot rotation, b1 pre-folded into P.
// DPP-reduce variant: 72.0-72.2 (reverted). Forced-MLP asm: 84.6 (reverted).
// Across R2-R7 this stage is invariant ~70 us under every compute/latency
// restructuring -> cache-hierarchy service bound on the 500 MB random gather.
__global__ __launch_bounds__(256, 3)
void edge_out(const __bf16* __restrict__ P, const int* __restrict__ src,
              const int* __restrict__ dst,
              const float* __restrict__ w3, const float* __restrict__ b3,
              const float* __restrict__ gamma, const float* __restrict__ beta,
              float* __restrict__ out) {
    const int tid = threadIdx.x;
    const int g   = tid >> 4;
    const int j   = tid & 15;

    float gv[16], btv[16], wv[16];
    {
        const float4* pg = (const float4*)(gamma + j * 16);
        const float4* pt = (const float4*)(beta + j * 16);
        const float4* pw = (const float4*)(w3 + j * 16);
        #pragma unroll
        for (int z = 0; z < 4; ++z) {
            float4 vg = pg[z], vt = pt[z], vw = pw[z];
            gv [z*4+0] = vg.x; gv [z*4+1] = vg.y; gv [z*4+2] = vg.z; gv [z*4+3] = vg.w;
            btv[z*4+0] = vt.x; btv[z*4+1] = vt.y; btv[z*4+2] = vt.z; btv[z*4+3] = vt.w;
            wv [z*4+0] = vw.x; wv [z*4+1] = vw.y; wv [z*4+2] = vw.z; wv [z*4+3] = vw.w;
        }
    }
    const float b3v = b3[0];
    const int e0 = blockIdx.x * 128 + g * 8;

    // preload this group's 8 src + 8 dst indices (lane j&7 holds edge e0+(j&7))
    int ep = e0 + (j & 7);
    if (ep >= EE) ep = EE - 1;
    const int sj = src[ep];
    const int dj = dst[ep];

    uint4 s0[3], s1[3], d0[3], d1[3];   // 3-slot rotation, static indices

    #pragma unroll
    for (int i = 0; i < 2; ++i) {       // prologue: edges 0 and 1 in flight
        int s = __shfl(sj, i, 16);
        int d = __shfl(dj, i, 16);
        const uint4* ps = (const uint4*)(P + (size_t)s * 512 + j * 16);
        const uint4* pd = (const uint4*)(P + (size_t)d * 512 + 256 + j * 16);
        s0[i] = ps[0]; s1[i] = ps[1]; d0[i] = pd[0]; d1[i] = pd[1];
    }

    #pragma unroll
    for (int i = 0; i < 8; ++i) {
        if (i + 2 < 8) {                // prefetch edge i+2
            const int slot = (i + 2) % 3;
            int s = __shfl(sj, i + 2, 16);
            int d = __shfl(dj, i + 2, 16);
            const uint4* ps = (const uint4*)(P + (size_t)s * 512 + j * 16);
            const uint4* pd = (const uint4*)(P + (size_t)d * 512 + 256 + j * 16);
            s0[slot] = ps[0]; s1[slot] = ps[1]; d0[slot] = pd[0]; d1[slot] = pd[1];
        }
        const int cs = i % 3;
        bf16x8 a0 = __builtin_bit_cast(bf16x8, s0[cs]);
        bf16x8 a1 = __builtin_bit_cast(bf16x8, s1[cs]);
        bf16x8 c0 = __builtin_bit_cast(bf16x8, d0[cs]);
        bf16x8 c1 = __builtin_bit_cast(bf16x8, d1[cs]);
        float x[16];
        #pragma unroll
        for (int z = 0; z < 8; ++z) {
            x[z]     = (float)a0[z] + (float)c0[z];     // b1 already folded in P
            x[z + 8] = (float)a1[z] + (float)c1[z];
        }
        float sum = 0.f, sq = 0.f;
        #pragma unroll
        for (int z = 0; z < 16; ++z) {
            sum += x[z];
            sq   = fmaf(x[z], x[z], sq);
        }
        #pragma unroll
        for (int m = 1; m < 16; m <<= 1) {
            sum += __shfl_xor(sum, m);
            sq  += __shfl_xor(sq,  m);
        }
        float mu = sum * (1.0f / 256.0f);
        float rs = rsqrtf(sq * (1.0f / 256.0f) - mu * mu + LN_EPS);
        float dot = 0.f;
        #pragma unroll
        for (int z = 0; z < 16; ++z) {
            float y = fmaxf((x[z] - mu) * rs * gv[z] + btv[z], 0.f);
            dot = fmaf(y, wv[z], dot);
        }
        #pragma unroll
        for (int m = 1; m < 16; m <<= 1) dot += __shfl_xor(dot, m);
        int e = e0 + i;
        if (j == 0 && e < EE) out[e] = dot + b3v;
    }

    // keep-alive (matches the measured-best build exactly)
    #pragma unroll
    for (int z = 0; z < 16; ++z)
        asm volatile("" :: "v"(gv[z]), "v"(btv[z]), "v"(wv[z]));
}

extern "C" void kernel_launch(void* const* d_in, const int* in_sizes, int n_in,
                              void* d_out, int out_size, void* d_ws, size_t ws_size,
                              hipStream_t stream) {
    const float* h_all  = (const float*)d_in[0];
    const int*   src    = (const int*)  d_in[1];
    const int*   dst    = (const int*)  d_in[2];
    const float* W1     = (const float*)d_in[3];
    const float* b1     = (const float*)d_in[4];
    const float* W3     = (const float*)d_in[5];
    const float* b3     = (const float*)d_in[6];
    const float* gamma2 = (const float*)d_in[7];
    const float* beta2  = (const float*)d_in[8];
    float* out = (float*)d_out;

    __bf16* w2c = (__bf16*)d_ws;                       // 131072 bf16 = 256 KB
    __bf16* P   = w2c + 131072;                        // 50000*512 bf16 = 51.2 MB

    w2_conv<<<64, 256, 0, stream>>>(W1, w2c);
    node_proj<<<(NN + 127) / 128, 256, 0, stream>>>(h_all, w2c, b1, P);
    edge_out<<<(EE + 127) / 128, 256, 0, stream>>>(P, src, dst, W3, b3,
                                                   gamma2, beta2, out);
}